// Round 1
// baseline (168.108 us; speedup 1.0000x reference)
//
#include <hip/hip_runtime.h>

// DFMBPSROIAlign: N ROIs x 49 parts x 10 channels, 4x4 bilinear samples/part.
// Strategy: one block per (part, n-chunk). Stage the part's 10x34x34 slab
// (46.2 KB) in LDS; each thread handles one (n, p) and loops c in registers.

constexpr int C  = 10;
constexpr int PH = 7;
constexpr int PW = 7;
constexpr int H  = 34;
constexpr int W  = 34;
constexpr int P  = PH * PW;     // 49
constexpr int HW = H * W;       // 1156
constexpr int FT_C_STRIDE = P * HW; // 56644

__global__ __launch_bounds__(256) void dfmb_psroi_kernel(
    const float* __restrict__ ft,
    const float* __restrict__ rois,
    float* __restrict__ out,
    int N)
{
    __shared__ float tile[C * HW]; // 46240 B

    const int p  = blockIdx.y;
    const int ph = p / PW;
    const int pw = p - ph * PW;

    // Cooperative load of this part's slab: tile[c][y*W+x]
    const float* __restrict__ src = ft + p * HW;
    for (int i = threadIdx.x; i < C * HW; i += 256) {
        int c = i / HW;
        int r = i - c * HW;
        tile[i] = src[c * FT_C_STRIDE + r];
    }
    __syncthreads();

    const int n = blockIdx.x * 256 + threadIdx.x;
    if (n >= N) return;

    float sum[C];
#pragma unroll
    for (int c = 0; c < C; ++c) sum[c] = 0.0f;
    float count = 0.0f;

    // Coordinate setup — contraction OFF so floor() arguments are plain
    // mul+add rounded, matching the un-fused reference computation.
    float wstart, hstart, sub_w, sub_h;
    {
#pragma clang fp contract(off)
        const float inv_stride = 0.0625f;        // /16 exact
        float rsw = rois[n * 5 + 1] * inv_stride;
        float rsh = rois[n * 5 + 2] * inv_stride;
        float rew = rois[n * 5 + 3] * inv_stride;
        float reh = rois[n * 5 + 4] * inv_stride;
        float roi_h = reh - rsh; if (!(roi_h > 0.1f)) roi_h = 0.1f;
        float roi_w = rew - rsw; if (!(roi_w > 0.1f)) roi_w = 0.1f;
        float bin_h = roi_h / 7.0f;              // keep true division
        float bin_w = roi_w / 7.0f;
        sub_h = bin_h * 0.25f;                   // /4 exact
        sub_w = bin_w * 0.25f;
        hstart = floorf(rsh + (float)ph * bin_h);
        wstart = floorf(rsw + (float)pw * bin_w);
    }

#pragma unroll
    for (int ih = 0; ih < 4; ++ih) {
#pragma unroll
        for (int iw = 0; iw < 4; ++iw) {
            float w, h;
            {
#pragma clang fp contract(off)
                w = wstart + ((float)iw + 0.5f) * sub_w;
                h = hstart + ((float)ih + 0.5f) * sub_h;
            }
            if (!(w > -1.0f && w < 34.0f && h > -1.0f && h < 34.0f)) continue;
            count += 1.0f;

            float x1f = floorf(w), x2f = ceilf(w);
            float y1f = floorf(h), y2f = ceilf(h);
            float x1v = (x1f >= 0.0f && x1f < 34.0f) ? 1.0f : 0.0f;
            float x2v = (x2f >= 0.0f && x2f < 34.0f) ? 1.0f : 0.0f;
            float y1v = (y1f >= 0.0f && y1f < 34.0f) ? 1.0f : 0.0f;
            float y2v = (y2f >= 0.0f && y2f < 34.0f) ? 1.0f : 0.0f;
            int x1 = (int)fminf(fmaxf(x1f, 0.0f), 33.0f);
            int x2 = (int)fminf(fmaxf(x2f, 0.0f), 33.0f);
            int y1 = (int)fminf(fmaxf(y1f, 0.0f), 33.0f);
            int y2 = (int)fminf(fmaxf(y2f, 0.0f), 33.0f);
            // distances vs CLAMPED corners (reference semantics)
            float dx = w - (float)x1;
            float dy = h - (float)y1;

            float w11 = (1.0f - dx) * (1.0f - dy) * (x1v * y1v);
            float w12 = (1.0f - dx) * dy          * (x1v * y2v);
            float w21 = dx          * (1.0f - dy) * (x2v * y1v);
            float w22 = dx          * dy          * (x2v * y2v);

            int o11 = y1 * W + x1;
            int o12 = y2 * W + x1;
            int o21 = y1 * W + x2;
            int o22 = y2 * W + x2;

#pragma unroll
            for (int c = 0; c < C; ++c) {
                const int b = c * HW; // compile-time per unrolled c -> imm offset
                sum[c] += w11 * tile[b + o11] + w12 * tile[b + o12]
                        + w21 * tile[b + o21] + w22 * tile[b + o22];
            }
        }
    }

    float cnt = count > 0.0f ? count : 1.0f;
    float inv = 1.0f / cnt;
    float* __restrict__ o = out + (size_t)n * (C * P) + p;
#pragma unroll
    for (int c = 0; c < C; ++c)
        o[c * P] = sum[c] * inv;
}

extern "C" void kernel_launch(void* const* d_in, const int* in_sizes, int n_in,
                              void* d_out, int out_size, void* d_ws, size_t ws_size,
                              hipStream_t stream) {
    const float* ft   = (const float*)d_in[0];
    const float* rois = (const float*)d_in[1];
    float* out = (float*)d_out;
    const int N = in_sizes[1] / 5; // rois is (N,5)
    dim3 grid((N + 255) / 256, P);
    dfmb_psroi_kernel<<<grid, dim3(256), 0, stream>>>(ft, rois, out, N);
}